// Round 4
// baseline (1397.579 us; speedup 1.0000x reference)
//
#include <hip/hip_runtime.h>

#define DEV __device__ __forceinline__

typedef __bf16 bf16x8 __attribute__((ext_vector_type(8)));
typedef float f32x4 __attribute__((ext_vector_type(4)));

DEV unsigned short f2bf(float f) {
    unsigned u = __builtin_bit_cast(unsigned, f);
    u += 0x7fffu + ((u >> 16) & 1u);   // round-to-nearest-even
    return (unsigned short)(u >> 16);
}

// zero counts[N] + stats[1536]; block 0 also detects int64-vs-int32 edge_index
// layout (odd 32-bit words all zero since node ids < 50000).
__global__ __launch_bounds__(256) void setup_kernel(
    const int* __restrict__ ei, int* __restrict__ flag,
    int* __restrict__ counts, float* __restrict__ stats, int N)
{
    int i = blockIdx.x * 256 + threadIdx.x;
    if (i < N) counts[i] = 0;
    if (i < 1536) stats[i] = 0.f;
    if (blockIdx.x == 0 && threadIdx.x < 64) {
        int t = threadIdx.x;
        int v = (t < 32) ? ei[2 * t + 1] : 0;
        unsigned long long b = __ballot(v == 0);
        if (t == 0) *flag = (b == ~0ull) ? 1 : 0;
    }
}

__global__ __launch_bounds__(256) void hist_kernel(
    const int* __restrict__ ei, const int* __restrict__ i64flag,
    int* __restrict__ counts, int E)
{
    int e = blockIdx.x * 256 + threadIdx.x;
    if (e >= E) return;
    int d = (*i64flag) ? ei[2 * (size_t)E + 2 * (size_t)e] : ei[(size_t)E + e];
    atomicAdd(&counts[d], 1);
}

// block-level inclusive scan; writes per-element exclusive offsets + block totals
__global__ __launch_bounds__(256) void scan1_kernel(
    const int* __restrict__ counts, int* __restrict__ offs,
    int* __restrict__ bsum, int N)
{
    __shared__ int s[256];
    int tid = threadIdx.x;
    int i = blockIdx.x * 256 + tid;
    int c = (i < N) ? counts[i] : 0;
    s[tid] = c;
    __syncthreads();
#pragma unroll
    for (int off = 1; off < 256; off <<= 1) {
        int add = (tid >= off) ? s[tid - off] : 0;
        __syncthreads();
        s[tid] += add;
        __syncthreads();
    }
    int incl = s[tid];
    if (i < N) offs[i] = incl - c;            // exclusive within block
    if (tid == 255) bsum[blockIdx.x] = incl;  // block total
}

// parallel exclusive scan of block sums (nb <= 256 for N = 50000)
__global__ __launch_bounds__(256) void scan2_kernel(int* __restrict__ bsum, int nb)
{
    __shared__ int s[256];
    int tid = threadIdx.x;
    int v = (tid < nb) ? bsum[tid] : 0;
    s[tid] = v;
    __syncthreads();
#pragma unroll
    for (int off = 1; off < 256; off <<= 1) {
        int add = (tid >= off) ? s[tid - off] : 0;
        __syncthreads();
        s[tid] += add;
        __syncthreads();
    }
    if (tid < nb) bsum[tid] = s[tid] - v;     // exclusive
}

__global__ __launch_bounds__(256) void scan3_kernel(
    int* __restrict__ offs, const int* __restrict__ bsum,
    int* __restrict__ cursor, int N)
{
    int i = blockIdx.x * 256 + threadIdx.x;
    if (i < N) {
        int o = offs[i] + bsum[blockIdx.x];
        offs[i] = o;
        cursor[i] = o;
    }
}

// CSR scatter: src_perm[slot] = src node; eslot[e] = slot (CSR position of edge e)
__global__ __launch_bounds__(256) void scatter_kernel(
    const int* __restrict__ ei, const int* __restrict__ i64flag,
    int* __restrict__ cursor, int* __restrict__ src_perm,
    int* __restrict__ eslot, int E)
{
    int e = blockIdx.x * 256 + threadIdx.x;
    if (e >= E) return;
    int s, d;
    if (*i64flag) {
        s = ei[2 * (size_t)e];
        d = ei[2 * (size_t)E + 2 * (size_t)e];
    } else {
        s = ei[e];
        d = ei[(size_t)E + e];
    }
    int pos = atomicAdd(&cursor[d], 1);
    src_perm[pos] = s;
    eslot[e] = pos;
}

// permute edge_attr rows into CSR order: ea_perm[eslot[e]] = ea[e].
// Read is fully sequential (NT stream); write is a random full-line 512B row.
__global__ __launch_bounds__(256) void permute_kernel(
    const float* __restrict__ ea, const int* __restrict__ eslot,
    float* __restrict__ eap, int E)
{
    int g = blockIdx.x * 256 + threadIdx.x;
    int e = g >> 5;                  // half-wave (32 lanes) per edge row
    if (e >= E) return;
    int d0 = (g & 31) * 4;
    int slot = eslot[e];
    f32x4 v = __builtin_nontemporal_load((const f32x4*)(ea + (size_t)e * 128 + d0));
    __builtin_nontemporal_store(v, (f32x4*)(eap + (size_t)slot * 128 + d0));
}

// ---------------- aggregation ----------------
// t1[n] (bf16) = xbn[n] + sum_{slot in CSR[n]} relu(xbn[src_perm[slot]] + eap[slot])
// xbn = AFFINE ? relu(x*sc + sh) : x  (outer BN+ReLU of previous layer folded in).
// One wave per node; lanes 0-31 take even CSR slots, lanes 32-63 odd slots;
// each lane covers 4 dims (float4). eap is streamed sequentially (CSR order).
template<bool AFFINE>
__global__ __launch_bounds__(512) void agg_kernel(
    const float* __restrict__ x, const float* __restrict__ eap,
    const int* __restrict__ srcp, const int* __restrict__ offs,
    const int* __restrict__ cnts,
    const float* __restrict__ statsIn, const float* __restrict__ gamma,
    const float* __restrict__ beta,
    unsigned short* __restrict__ t1, int N)
{
    __shared__ float sc[128], sh[128];
    int tid = threadIdx.x;
    if (AFFINE) {
        if (tid < 128) {
            float inv = 1.f / (float)N;
            float m = statsIn[tid] * inv;
            float v = statsIn[128 + tid] * inv - m * m;
            v = fmaxf(v, 0.f);
            float rs = rsqrtf(v + 1e-5f);
            float gr = gamma[tid] * rs;
            sc[tid] = gr;
            sh[tid] = beta[tid] - m * gr;
        }
        __syncthreads();
    }

    const int lane = tid & 63;
    const int half = lane >> 5;        // 0: even slots, 1: odd slots
    const int l32  = lane & 31;
    const int d0   = l32 * 4;

    f32x4 scv = {1.f, 1.f, 1.f, 1.f}, shv = {0.f, 0.f, 0.f, 0.f};
    if (AFFINE) {
        scv = *(const f32x4*)(sc + d0);
        shv = *(const f32x4*)(sh + d0);
    }

    const int n = blockIdx.x * 8 + (tid >> 6);
    if (n >= N) return;

    const int start = offs[n];
    const int deg = cnts[n];

    f32x4 acc = {0.f, 0.f, 0.f, 0.f};
    if (half == 0) {
        f32x4 cv = *(const f32x4*)(x + (size_t)n * 128 + d0);
        if (AFFINE) {
#pragma unroll
            for (int q = 0; q < 4; ++q)
                cv[q] = fmaxf(fmaf(cv[q], scv[q], shv[q]), 0.f);
        }
        acc = cv;
    }

#define EDGE_TERM(S, SLOT) { \
    f32x4 gx = *(const f32x4*)(x + (size_t)(S) * 128 + d0); \
    f32x4 av = __builtin_nontemporal_load((const f32x4*)(eap + (size_t)(SLOT) * 128 + d0)); \
    if (AFFINE) { \
        _Pragma("unroll") \
        for (int q = 0; q < 4; ++q) gx[q] = fmaxf(fmaf(gx[q], scv[q], shv[q]), 0.f); \
    } \
    _Pragma("unroll") \
    for (int q = 0; q < 4; ++q) acc[q] += fmaxf(gx[q] + av[q], 0.f); }

    int j = half;
    for (; j + 2 < deg; j += 4) {     // this half's slots: j and j+2 both valid
        int s0 = srcp[start + j];
        int s1 = srcp[start + j + 2];
        EDGE_TERM(s0, start + j);
        EDGE_TERM(s1, start + j + 2);
    }
    for (; j < deg; j += 2) {
        int s0 = srcp[start + j];
        EDGE_TERM(s0, start + j);
    }
#undef EDGE_TERM

    // combine the two half-wave partial sums
#pragma unroll
    for (int q = 0; q < 4; ++q) acc[q] += __shfl_xor(acc[q], 32);

    if (half == 0) {
        ushort4 o;
        o.x = f2bf(acc[0]); o.y = f2bf(acc[1]);
        o.z = f2bf(acc[2]); o.w = f2bf(acc[3]);
        *(ushort4*)(t1 + (size_t)n * 128 + d0) = o;
    }
}

// ---------------- GEMM with fused BN-affine on A (optional) + fused col stats
// out[n][c] = sum_k a[n][k]*W[k][c] + bias[c].
// BNA=false: inp is bf16 [N][128] (pre-rounded), copied straight to LDS.
// BNA=true:  inp is f32  [N][128]; a = relu(inp*sc+sh) rounded to bf16.
// Also accumulates column sum/sumsq of out into statsOut[0..127]/[128..255].
template<bool BNA>
__global__ __launch_bounds__(256) void gemm_kernel(
    const void* __restrict__ inp,
    const float* __restrict__ W,      // [128][128] f32, [k][c]
    const float* __restrict__ bias,   // [128] f32
    const float* __restrict__ statsIn,
    const float* __restrict__ gA, const float* __restrict__ bA,
    float* __restrict__ out, float* __restrict__ statsOut, int N)
{
    __shared__ __attribute__((aligned(16))) unsigned short As[64][136];   // [r][k]
    __shared__ __attribute__((aligned(16))) unsigned short Ws[128][136];  // [c][k]
    __shared__ float u0[128], u1[128];  // BNA: sc/sh during staging; then cs/cq
    const int tid = threadIdx.x;
    const int row0 = blockIdx.x * 64;

    if (BNA) {
        if (tid < 128) {
            float inv = 1.f / (float)N;
            float m = statsIn[tid] * inv;
            float v = statsIn[128 + tid] * inv - m * m;
            v = fmaxf(v, 0.f);
            float rs = rsqrtf(v + 1e-5f);
            float gr = gA[tid] * rs;
            u0[tid] = gr;
            u1[tid] = bA[tid] - m * gr;
        }
        __syncthreads();
    }

    // stage W transposed as bf16: Ws[c][k] = W[k*128+c]
#pragma unroll
    for (int it = 0; it < 8; ++it) {
        int lin = (it * 256 + tid) * 8;
        int k = lin >> 7;
        int c = lin & 127;
        const float* wp = W + (size_t)k * 128 + c;
        float4 wa = *(const float4*)wp;
        float4 wb = *(const float4*)(wp + 4);
        Ws[c + 0][k] = f2bf(wa.x); Ws[c + 1][k] = f2bf(wa.y);
        Ws[c + 2][k] = f2bf(wa.z); Ws[c + 3][k] = f2bf(wa.w);
        Ws[c + 4][k] = f2bf(wb.x); Ws[c + 5][k] = f2bf(wb.y);
        Ws[c + 6][k] = f2bf(wb.z); Ws[c + 7][k] = f2bf(wb.w);
    }
    // stage A tile (zero-pad tail rows)
    if (BNA) {
        const float* ip = (const float*)inp;
#pragma unroll
        for (int it = 0; it < 8; ++it) {
            int lin = (it * 256 + tid) * 4;
            int r = lin >> 7;
            int c = lin & 127;
            int row = row0 + r;
            if (row < N) {
                float4 v = *(const float4*)(ip + (size_t)row * 128 + c);
                v.x = fmaxf(fmaf(v.x, u0[c + 0], u1[c + 0]), 0.f);
                v.y = fmaxf(fmaf(v.y, u0[c + 1], u1[c + 1]), 0.f);
                v.z = fmaxf(fmaf(v.z, u0[c + 2], u1[c + 2]), 0.f);
                v.w = fmaxf(fmaf(v.w, u0[c + 3], u1[c + 3]), 0.f);
                As[r][c + 0] = f2bf(v.x); As[r][c + 1] = f2bf(v.y);
                As[r][c + 2] = f2bf(v.z); As[r][c + 3] = f2bf(v.w);
            } else {
                As[r][c + 0] = 0; As[r][c + 1] = 0; As[r][c + 2] = 0; As[r][c + 3] = 0;
            }
        }
    } else {
        const unsigned short* ip = (const unsigned short*)inp;
#pragma unroll
        for (int it = 0; it < 4; ++it) {
            int lin = (it * 256 + tid) * 8;
            int r = lin >> 7;
            int c = lin & 127;
            int row = row0 + r;
            uint4 v = {0u, 0u, 0u, 0u};
            if (row < N) v = *(const uint4*)(ip + (size_t)row * 128 + c);
            *(uint4*)&As[r][c] = v;
        }
    }
    __syncthreads();
    // repurpose u0/u1 as column sum / sumsq accumulators
    if (tid < 128) { u0[tid] = 0.f; u1[tid] = 0.f; }
    __syncthreads();

    const int wave = tid >> 6;
    const int lane = tid & 63;
    const int quad = lane >> 4;
    const int m16  = lane & 15;

    // A fragments: A[m=lane&15][k=quad*8+j], 8 contiguous bf16 -> ds_read_b128
    bf16x8 af[4];
#pragma unroll
    for (int kk = 0; kk < 4; ++kk)
        af[kk] = *reinterpret_cast<const bf16x8*>(&As[wave * 16 + m16][kk * 32 + quad * 8]);

#pragma unroll
    for (int ct = 0; ct < 8; ++ct) {
        f32x4 acc = {0.f, 0.f, 0.f, 0.f};
#pragma unroll
        for (int kk = 0; kk < 4; ++kk) {
            bf16x8 bf = *reinterpret_cast<const bf16x8*>(&Ws[ct * 16 + m16][kk * 32 + quad * 8]);
            acc = __builtin_amdgcn_mfma_f32_16x16x32_bf16(af[kk], bf, acc, 0, 0, 0);
        }
        int col = ct * 16 + m16;
        float bb = bias[col];
        float s_part = 0.f, q_part = 0.f;
#pragma unroll
        for (int r = 0; r < 4; ++r) {
            int row = row0 + wave * 16 + quad * 4 + r;  // C/D: row = quad*4+reg, col = lane&15
            if (row < N) {
                float val = acc[r] + bb;
                out[(size_t)row * 128 + col] = val;
                s_part += val;
                q_part += val * val;
            }
        }
        // reduce over the 4 quad-groups that share this column (lanes ^16, ^32)
        s_part += __shfl_xor(s_part, 16); q_part += __shfl_xor(q_part, 16);
        s_part += __shfl_xor(s_part, 32); q_part += __shfl_xor(q_part, 32);
        if (lane < 16) {
            atomicAdd(&u0[col], s_part);
            atomicAdd(&u1[col], q_part);
        }
    }
    __syncthreads();
    if (tid < 128) {
        atomicAdd(&statsOut[tid],       u0[tid]);
        atomicAdd(&statsOut[128 + tid], u1[tid]);
    }
}

// out = gamma * (t - mean) * rsqrt(var + eps) + beta  (final layer, no relu)
__global__ __launch_bounds__(256) void bn_kernel(
    const float* __restrict__ t, const float* __restrict__ sum, const float* __restrict__ sq,
    const float* __restrict__ gamma, const float* __restrict__ beta,
    float* __restrict__ out, int N, int nv4)
{
    __shared__ float sc[128], sh[128];
    int tid = threadIdx.x;
    if (tid < 128) {
        float inv = 1.f / (float)N;
        float m = sum[tid] * inv;
        float v = sq[tid] * inv - m * m;
        v = fmaxf(v, 0.f);
        float rs = rsqrtf(v + 1e-5f);
        float gr = gamma[tid] * rs;
        sc[tid] = gr;
        sh[tid] = beta[tid] - m * gr;
    }
    __syncthreads();
    int g = blockIdx.x * 256 + tid;
    if (g < nv4) {
        int c = (g & 31) * 4;
        float4 v = *(const float4*)(t + (size_t)g * 4);
        float4 o;
        o.x = v.x * sc[c + 0] + sh[c + 0];
        o.y = v.y * sc[c + 1] + sh[c + 1];
        o.z = v.z * sc[c + 2] + sh[c + 2];
        o.w = v.w * sc[c + 3] + sh[c + 3];
        *(float4*)(out + (size_t)g * 4) = o;
    }
}

extern "C" void kernel_launch(void* const* d_in, const int* in_sizes, int n_in,
                              void* d_out, int out_size, void* d_ws, size_t ws_size,
                              hipStream_t stream)
{
    const float* x  = (const float*)d_in[0];
    const int* ei   = (const int*)d_in[1];
    const float* ea = (const float*)d_in[2];
    // d_in[3] = batch (unused)
    const float* W1 = (const float*)d_in[4];
    const float* b1 = (const float*)d_in[5];
    const float* gm = (const float*)d_in[6];
    const float* bm = (const float*)d_in[7];
    const float* W2 = (const float*)d_in[8];
    const float* b2 = (const float*)d_in[9];
    const float* go = (const float*)d_in[10];
    const float* bo = (const float*)d_in[11];
    float* out = (float*)d_out;

    const int N = in_sizes[0] / 128;   // 50000
    const int E = in_sizes[2] / 128;   // 800000

    char* w = (char*)d_ws;
    float* t2   = (float*)w;            w += (size_t)N * 128 * 4;   // gemm1 out (pre-BN1)
    float* t3   = (float*)w;            w += (size_t)N * 128 * 4;   // gemm2 out (pre-BN2)
    unsigned short* t1 = (unsigned short*)w; w += (size_t)N * 128 * 2;  // agg out, bf16
    float* stats = (float*)w;           w += 1536 * 4;              // 6 x (sum[128], sq[128])
    int* i64flag = (int*)w;             w += 16;
    int* counts  = (int*)w;             w += (size_t)N * 4;
    int* offs    = (int*)w;             w += (size_t)N * 4;
    int* cursor  = (int*)w;             w += (size_t)N * 4;
    int* bsum    = (int*)w;             w += 256 * 4;
    int* eslot   = (int*)w;             w += (size_t)E * 4;         // edge -> CSR slot
    int* srcp    = (int*)w;             w += (size_t)E * 4;         // CSR slot -> src node
    float* eap   = (float*)w;           w += (size_t)E * 128 * 4;   // ea permuted to CSR order

    const int nv4 = N * 32;
    const int gElem = (nv4 + 255) / 256;
    const int gGemm = (N + 63) / 64;
    const int gEdge = (E + 255) / 256;
    const int nb    = (N + 255) / 256;
    const int gAgg  = (N + 7) / 8;
    const int gPerm = ((E * 32) + 255) / 256;

    // ---- CSR build + ea permute (edge structure is identical across layers) ----
    setup_kernel<<<nb, 256, 0, stream>>>(ei, i64flag, counts, stats, N);
    hist_kernel<<<gEdge, 256, 0, stream>>>(ei, i64flag, counts, E);
    scan1_kernel<<<nb, 256, 0, stream>>>(counts, offs, bsum, N);
    scan2_kernel<<<1, 256, 0, stream>>>(bsum, nb);
    scan3_kernel<<<nb, 256, 0, stream>>>(offs, bsum, cursor, N);
    scatter_kernel<<<gEdge, 256, 0, stream>>>(ei, i64flag, cursor, srcp, eslot, E);
    permute_kernel<<<gPerm, 256, 0, stream>>>(ea, eslot, eap, E);

    for (int i = 0; i < 3; ++i) {
        float* sMlp = stats + (size_t)i * 512;        // gemm1 output stats
        float* sOut = stats + (size_t)i * 512 + 256;  // gemm2 output stats

        if (i == 0) {
            agg_kernel<false><<<gAgg, 512, 0, stream>>>(
                x, eap, srcp, offs, counts, nullptr, nullptr, nullptr, t1, N);
        } else {
            float* sPrev = stats + (size_t)(i - 1) * 512 + 256;
            agg_kernel<true><<<gAgg, 512, 0, stream>>>(
                t3, eap, srcp, offs, counts, sPrev, go + (i - 1) * 128, bo + (i - 1) * 128, t1, N);
        }
        gemm_kernel<false><<<gGemm, 256, 0, stream>>>(
            t1, W1 + (size_t)i * 16384, b1 + i * 128,
            nullptr, nullptr, nullptr, t2, sMlp, N);
        gemm_kernel<true><<<gGemm, 256, 0, stream>>>(
            t2, W2 + (size_t)i * 16384, b2 + i * 128,
            sMlp, gm + i * 128, bm + i * 128, t3, sOut, N);
    }
    // final outer BN (no relu) -> out
    bn_kernel<<<gElem, 256, 0, stream>>>(t3, stats + 2 * 512 + 256, stats + 2 * 512 + 384,
                                         go + 256, bo + 256, out, N, nv4);
}

// Round 5
// 1149.995 us; speedup vs baseline: 1.2153x; 1.2153x over previous
//
#include <hip/hip_runtime.h>

#define DEV __device__ __forceinline__

typedef __bf16 bf16x8 __attribute__((ext_vector_type(8)));
typedef float f32x4 __attribute__((ext_vector_type(4)));

DEV unsigned short f2bf(float f) {
    unsigned u = __builtin_bit_cast(unsigned, f);
    u += 0x7fffu + ((u >> 16) & 1u);   // round-to-nearest-even
    return (unsigned short)(u >> 16);
}

// zero counts[N] + stats[1536]; pre-convert W1,W2 (6 mats) to bf16 [c][k];
// block 0 detects int64-vs-int32 edge_index layout.
__global__ __launch_bounds__(256) void setup_kernel(
    const int* __restrict__ ei, int* __restrict__ flag,
    int* __restrict__ counts, float* __restrict__ stats,
    const float* __restrict__ W1, const float* __restrict__ W2,
    unsigned short* __restrict__ Wt, int N)
{
    int g = blockIdx.x * 256 + threadIdx.x;
    if (g < N) counts[g] = 0;
    if (g < 1536) stats[g] = 0.f;
    if (g < 12288) {                       // 6 mats x 16 k-groups x 128 cols
        int mat = g >> 11;
        int r = g & 2047;
        int c = r & 127;
        int kg = (r >> 7) * 8;
        const float* Wsrc = (mat < 3) ? (W1 + (size_t)mat * 16384)
                                      : (W2 + (size_t)(mat - 3) * 16384);
        unsigned short o[8];
#pragma unroll
        for (int q = 0; q < 8; ++q)
            o[q] = f2bf(Wsrc[(size_t)(kg + q) * 128 + c]);
        *(uint4*)(Wt + ((size_t)mat * 128 + c) * 128 + kg) = *(const uint4*)o;
    }
    if (blockIdx.x == 0 && threadIdx.x < 64) {
        int t = threadIdx.x;
        int v = (t < 32) ? ei[2 * t + 1] : 0;
        unsigned long long b = __ballot(v == 0);
        if (t == 0) *flag = (b == ~0ull) ? 1 : 0;
    }
}

__global__ __launch_bounds__(256) void hist_kernel(
    const int* __restrict__ ei, const int* __restrict__ i64flag,
    int* __restrict__ counts, int E)
{
    int e = blockIdx.x * 256 + threadIdx.x;
    if (e >= E) return;
    int d = (*i64flag) ? ei[2 * (size_t)E + 2 * (size_t)e] : ei[(size_t)E + e];
    atomicAdd(&counts[d], 1);
}

// block-level inclusive scan; writes per-element exclusive offsets + block totals
__global__ __launch_bounds__(256) void scan1_kernel(
    const int* __restrict__ counts, int* __restrict__ offs,
    int* __restrict__ bsum, int N)
{
    __shared__ int s[256];
    int tid = threadIdx.x;
    int i = blockIdx.x * 256 + tid;
    int c = (i < N) ? counts[i] : 0;
    s[tid] = c;
    __syncthreads();
#pragma unroll
    for (int off = 1; off < 256; off <<= 1) {
        int add = (tid >= off) ? s[tid - off] : 0;
        __syncthreads();
        s[tid] += add;
        __syncthreads();
    }
    int incl = s[tid];
    if (i < N) offs[i] = incl - c;            // exclusive within block
    if (tid == 255) bsum[blockIdx.x] = incl;  // block total
}

// parallel exclusive scan of block sums (nb <= 256 for N = 50000)
__global__ __launch_bounds__(256) void scan2_kernel(int* __restrict__ bsum, int nb)
{
    __shared__ int s[256];
    int tid = threadIdx.x;
    int v = (tid < nb) ? bsum[tid] : 0;
    s[tid] = v;
    __syncthreads();
#pragma unroll
    for (int off = 1; off < 256; off <<= 1) {
        int add = (tid >= off) ? s[tid - off] : 0;
        __syncthreads();
        s[tid] += add;
        __syncthreads();
    }
    if (tid < nb) bsum[tid] = s[tid] - v;     // exclusive
}

__global__ __launch_bounds__(256) void scan3_kernel(
    int* __restrict__ offs, const int* __restrict__ bsum,
    int* __restrict__ cursor, int N)
{
    int i = blockIdx.x * 256 + threadIdx.x;
    if (i < N) {
        int o = offs[i] + bsum[blockIdx.x];
        offs[i] = o;
        cursor[i] = o;
    }
}

// CSR scatter: el[slot] = (src, edge_id)
__global__ __launch_bounds__(256) void scatter_kernel(
    const int* __restrict__ ei, const int* __restrict__ i64flag,
    int* __restrict__ cursor, int2* __restrict__ el, int E)
{
    int e = blockIdx.x * 256 + threadIdx.x;
    if (e >= E) return;
    int s, d;
    if (*i64flag) {
        s = ei[2 * (size_t)e];
        d = ei[2 * (size_t)E + 2 * (size_t)e];
    } else {
        s = ei[e];
        d = ei[(size_t)E + e];
    }
    int pos = atomicAdd(&cursor[d], 1);
    el[pos] = make_int2(s, e);
}

// ---------------- aggregation ----------------
// t1[n] (bf16) = xbn[n] + sum_{slot in CSR[n]} relu(xbn[el[slot].x] + ea[el[slot].y])
// xbn = AFFINE ? relu(x*sc + sh) : x  (outer BN+ReLU of previous layer folded in).
// One wave per node; half-wave 0 takes the first ceil(deg/2) CSR slots, half 1
// the rest (contiguous ranges -> index loads batch). 4-edge unroll: 4 el loads
// then 4 x-gathers + 4 NT ea loads in flight before any math (MLP test).
template<bool AFFINE>
__global__ __launch_bounds__(512) void agg_kernel(
    const float* __restrict__ x, const float* __restrict__ ea,
    const int2* __restrict__ el, const int* __restrict__ offs,
    const int* __restrict__ cnts,
    const float* __restrict__ statsIn, const float* __restrict__ gamma,
    const float* __restrict__ beta,
    unsigned short* __restrict__ t1, int N)
{
    __shared__ float sc[128], sh[128];
    int tid = threadIdx.x;
    if (AFFINE) {
        if (tid < 128) {
            float inv = 1.f / (float)N;
            float m = statsIn[tid] * inv;
            float v = statsIn[128 + tid] * inv - m * m;
            v = fmaxf(v, 0.f);
            float rs = rsqrtf(v + 1e-5f);
            float gr = gamma[tid] * rs;
            sc[tid] = gr;
            sh[tid] = beta[tid] - m * gr;
        }
        __syncthreads();
    }

    const int lane = tid & 63;
    const int half = lane >> 5;
    const int l32  = lane & 31;
    const int d0   = l32 * 4;

    f32x4 scv = {1.f, 1.f, 1.f, 1.f}, shv = {0.f, 0.f, 0.f, 0.f};
    if (AFFINE) {
        scv = *(const f32x4*)(sc + d0);
        shv = *(const f32x4*)(sh + d0);
    }

    const int n = blockIdx.x * 8 + (tid >> 6);
    if (n >= N) return;

    const int start = offs[n];
    const int deg = cnts[n];
    const int mid = (deg + 1) >> 1;
    int j        = half ? mid : 0;
    const int hi = half ? deg : mid;

    f32x4 acc = {0.f, 0.f, 0.f, 0.f};
    if (half == 0) {
        f32x4 cv = *(const f32x4*)(x + (size_t)n * 128 + d0);
        if (AFFINE) {
#pragma unroll
            for (int q = 0; q < 4; ++q)
                cv[q] = fmaxf(fmaf(cv[q], scv[q], shv[q]), 0.f);
        }
        acc = cv;
    }

#define APPLY(GX, AV) { \
    if (AFFINE) { \
        _Pragma("unroll") \
        for (int q = 0; q < 4; ++q) (GX)[q] = fmaxf(fmaf((GX)[q], scv[q], shv[q]), 0.f); \
    } \
    _Pragma("unroll") \
    for (int q = 0; q < 4; ++q) acc[q] += fmaxf((GX)[q] + (AV)[q], 0.f); }

    for (; j + 3 < hi; j += 4) {
        int2 e0 = el[start + j + 0];
        int2 e1 = el[start + j + 1];
        int2 e2 = el[start + j + 2];
        int2 e3 = el[start + j + 3];
        f32x4 x0 = *(const f32x4*)(x + (size_t)e0.x * 128 + d0);
        f32x4 x1 = *(const f32x4*)(x + (size_t)e1.x * 128 + d0);
        f32x4 x2 = *(const f32x4*)(x + (size_t)e2.x * 128 + d0);
        f32x4 x3 = *(const f32x4*)(x + (size_t)e3.x * 128 + d0);
        f32x4 a0 = __builtin_nontemporal_load((const f32x4*)(ea + (size_t)e0.y * 128 + d0));
        f32x4 a1 = __builtin_nontemporal_load((const f32x4*)(ea + (size_t)e1.y * 128 + d0));
        f32x4 a2 = __builtin_nontemporal_load((const f32x4*)(ea + (size_t)e2.y * 128 + d0));
        f32x4 a3 = __builtin_nontemporal_load((const f32x4*)(ea + (size_t)e3.y * 128 + d0));
        APPLY(x0, a0); APPLY(x1, a1); APPLY(x2, a2); APPLY(x3, a3);
    }
    for (; j < hi; ++j) {
        int2 e0 = el[start + j];
        f32x4 x0 = *(const f32x4*)(x + (size_t)e0.x * 128 + d0);
        f32x4 a0 = __builtin_nontemporal_load((const f32x4*)(ea + (size_t)e0.y * 128 + d0));
        APPLY(x0, a0);
    }
#undef APPLY

    // combine the two half-wave partial sums
#pragma unroll
    for (int q = 0; q < 4; ++q) acc[q] += __shfl_xor(acc[q], 32);

    if (half == 0) {
        ushort4 o;
        o.x = f2bf(acc[0]); o.y = f2bf(acc[1]);
        o.z = f2bf(acc[2]); o.w = f2bf(acc[3]);
        *(ushort4*)(t1 + (size_t)n * 128 + d0) = o;
    }
}

// ---------------- GEMM with fused BN-affine on A (optional) + fused col stats
// out[n][c] = sum_k a[n][k]*Wt[c][k] + bias[c].  Wt is pre-converted bf16 [c][k].
// BNA=false: inp is bf16 [N][128] (pre-rounded), copied straight to LDS.
// BNA=true:  inp is f32  [N][128]; a = relu(inp*sc+sh) rounded to bf16.
// Also accumulates column sum/sumsq of out into statsOut[0..127]/[128..255].
template<bool BNA>
__global__ __launch_bounds__(256) void gemm_kernel(
    const void* __restrict__ inp,
    const unsigned short* __restrict__ Wt,  // [128][128] bf16, [c][k]
    const float* __restrict__ bias,         // [128] f32
    const float* __restrict__ statsIn,
    const float* __restrict__ gA, const float* __restrict__ bA,
    float* __restrict__ out, float* __restrict__ statsOut, int N)
{
    __shared__ __attribute__((aligned(16))) unsigned short As[64][136];   // [r][k]
    __shared__ __attribute__((aligned(16))) unsigned short Ws[128][136];  // [c][k]
    __shared__ float u0[128], u1[128];  // BNA: sc/sh during staging; then cs/cq
    const int tid = threadIdx.x;
    const int row0 = blockIdx.x * 64;

    if (BNA) {
        if (tid < 128) {
            float inv = 1.f / (float)N;
            float m = statsIn[tid] * inv;
            float v = statsIn[128 + tid] * inv - m * m;
            v = fmaxf(v, 0.f);
            float rs = rsqrtf(v + 1e-5f);
            float gr = gA[tid] * rs;
            u0[tid] = gr;
            u1[tid] = bA[tid] - m * gr;
        }
        __syncthreads();
    }

    // stage Wt -> Ws (bf16 copy, coalesced)
#pragma unroll
    for (int it = 0; it < 8; ++it) {
        int lin = (it * 256 + tid) * 8;
        int c = lin >> 7;
        int k = lin & 127;
        *(uint4*)&Ws[c][k] = *(const uint4*)(Wt + (size_t)c * 128 + k);
    }
    // stage A tile (zero-pad tail rows)
    if (BNA) {
        const float* ip = (const float*)inp;
#pragma unroll
        for (int it = 0; it < 8; ++it) {
            int lin = (it * 256 + tid) * 4;
            int r = lin >> 7;
            int c = lin & 127;
            int row = row0 + r;
            if (row < N) {
                float4 v = *(const float4*)(ip + (size_t)row * 128 + c);
                v.x = fmaxf(fmaf(v.x, u0[c + 0], u1[c + 0]), 0.f);
                v.y = fmaxf(fmaf(v.y, u0[c + 1], u1[c + 1]), 0.f);
                v.z = fmaxf(fmaf(v.z, u0[c + 2], u1[c + 2]), 0.f);
                v.w = fmaxf(fmaf(v.w, u0[c + 3], u1[c + 3]), 0.f);
                As[r][c + 0] = f2bf(v.x); As[r][c + 1] = f2bf(v.y);
                As[r][c + 2] = f2bf(v.z); As[r][c + 3] = f2bf(v.w);
            } else {
                As[r][c + 0] = 0; As[r][c + 1] = 0; As[r][c + 2] = 0; As[r][c + 3] = 0;
            }
        }
    } else {
        const unsigned short* ip = (const unsigned short*)inp;
#pragma unroll
        for (int it = 0; it < 4; ++it) {
            int lin = (it * 256 + tid) * 8;
            int r = lin >> 7;
            int c = lin & 127;
            int row = row0 + r;
            uint4 v = {0u, 0u, 0u, 0u};
            if (row < N) v = *(const uint4*)(ip + (size_t)row * 128 + c);
            *(uint4*)&As[r][c] = v;
        }
    }
    __syncthreads();
    // repurpose u0/u1 as column sum / sumsq accumulators
    if (tid < 128) { u0[tid] = 0.f; u1[tid] = 0.f; }
    __syncthreads();

    const int wave = tid >> 6;
    const int lane = tid & 63;
    const int quad = lane >> 4;
    const int m16  = lane & 15;

    // A fragments: A[m=lane&15][k=quad*8+j], 8 contiguous bf16 -> ds_read_b128
    bf16x8 af[4];
#pragma unroll
    for (int kk = 0; kk < 4; ++kk)
        af[kk] = *reinterpret_cast<const bf16x8*>(&As[wave * 16 + m16][kk * 32 + quad * 8]);

#pragma unroll
    for (int ct = 0; ct < 8; ++ct) {
        f32x4 acc = {0.f, 0.f, 0.f, 0.f};
#pragma unroll
        for (int kk = 0; kk < 4; ++kk) {
            bf16x8 bf = *reinterpret_cast<const bf16x8*>(&Ws[ct * 16 + m16][kk * 32 + quad * 8]);
            acc = __builtin_amdgcn_mfma_f32_16x16x32_bf16(af[kk], bf, acc, 0, 0, 0);
        }
        int col = ct * 16 + m16;
        float bb = bias[col];
        float s_part = 0.f, q_part = 0.f;
#pragma unroll
        for (int r = 0; r < 4; ++r) {
            int row = row0 + wave * 16 + quad * 4 + r;  // C/D: row = quad*4+reg, col = lane&15
            if (row < N) {
                float val = acc[r] + bb;
                out[(size_t)row * 128 + col] = val;
                s_part += val;
                q_part += val * val;
            }
        }
        // reduce over the 4 quad-groups that share this column (lanes ^16, ^32)
        s_part += __shfl_xor(s_part, 16); q_part += __shfl_xor(q_part, 16);
        s_part += __shfl_xor(s_part, 32); q_part += __shfl_xor(q_part, 32);
        if (lane < 16) {
            atomicAdd(&u0[col], s_part);
            atomicAdd(&u1[col], q_part);
        }
    }
    __syncthreads();
    if (tid < 128) {
        atomicAdd(&statsOut[tid],       u0[tid]);
        atomicAdd(&statsOut[128 + tid], u1[tid]);
    }
}

// out = gamma * (t - mean) * rsqrt(var + eps) + beta  (final layer, no relu)
__global__ __launch_bounds__(256) void bn_kernel(
    const float* __restrict__ t, const float* __restrict__ sum, const float* __restrict__ sq,
    const float* __restrict__ gamma, const float* __restrict__ beta,
    float* __restrict__ out, int N, int nv4)
{
    __shared__ float sc[128], sh[128];
    int tid = threadIdx.x;
    if (tid < 128) {
        float inv = 1.f / (float)N;
        float m = sum[tid] * inv;
        float v = sq[tid] * inv - m * m;
        v = fmaxf(v, 0.f);
        float rs = rsqrtf(v + 1e-5f);
        float gr = gamma[tid] * rs;
        sc[tid] = gr;
        sh[tid] = beta[tid] - m * gr;
    }
    __syncthreads();
    int g = blockIdx.x * 256 + tid;
    if (g < nv4) {
        int c = (g & 31) * 4;
        float4 v = *(const float4*)(t + (size_t)g * 4);
        float4 o;
        o.x = v.x * sc[c + 0] + sh[c + 0];
        o.y = v.y * sc[c + 1] + sh[c + 1];
        o.z = v.z * sc[c + 2] + sh[c + 2];
        o.w = v.w * sc[c + 3] + sh[c + 3];
        *(float4*)(out + (size_t)g * 4) = o;
    }
}

extern "C" void kernel_launch(void* const* d_in, const int* in_sizes, int n_in,
                              void* d_out, int out_size, void* d_ws, size_t ws_size,
                              hipStream_t stream)
{
    const float* x  = (const float*)d_in[0];
    const int* ei   = (const int*)d_in[1];
    const float* ea = (const float*)d_in[2];
    // d_in[3] = batch (unused)
    const float* W1 = (const float*)d_in[4];
    const float* b1 = (const float*)d_in[5];
    const float* gm = (const float*)d_in[6];
    const float* bm = (const float*)d_in[7];
    const float* W2 = (const float*)d_in[8];
    const float* b2 = (const float*)d_in[9];
    const float* go = (const float*)d_in[10];
    const float* bo = (const float*)d_in[11];
    float* out = (float*)d_out;

    const int N = in_sizes[0] / 128;   // 50000
    const int E = in_sizes[2] / 128;   // 800000

    char* w = (char*)d_ws;
    float* t2   = (float*)w;            w += (size_t)N * 128 * 4;   // gemm1 out (pre-BN1)
    float* t3   = (float*)w;            w += (size_t)N * 128 * 4;   // gemm2 out (pre-BN2)
    unsigned short* t1 = (unsigned short*)w; w += (size_t)N * 128 * 2;  // agg out, bf16
    unsigned short* Wt = (unsigned short*)w; w += (size_t)6 * 16384 * 2; // W bf16 [c][k]
    float* stats = (float*)w;           w += 1536 * 4;              // 6 x (sum[128], sq[128])
    int* i64flag = (int*)w;             w += 16;
    int* counts  = (int*)w;             w += (size_t)N * 4;
    int* offs    = (int*)w;             w += (size_t)N * 4;
    int* cursor  = (int*)w;             w += (size_t)N * 4;
    int* bsum    = (int*)w;             w += 256 * 4;
    int2* el     = (int2*)w;            w += (size_t)E * 8;         // CSR: (src, edge)

    const int nv4 = N * 32;
    const int gElem = (nv4 + 255) / 256;
    const int gGemm = (N + 63) / 64;
    const int gEdge = (E + 255) / 256;
    const int nb    = (N + 255) / 256;
    const int gAgg  = (N + 7) / 8;

    // ---- CSR build + W pre-convert (both layer-invariant) ----
    setup_kernel<<<nb, 256, 0, stream>>>(ei, i64flag, counts, stats, W1, W2, Wt, N);
    hist_kernel<<<gEdge, 256, 0, stream>>>(ei, i64flag, counts, E);
    scan1_kernel<<<nb, 256, 0, stream>>>(counts, offs, bsum, N);
    scan2_kernel<<<1, 256, 0, stream>>>(bsum, nb);
    scan3_kernel<<<nb, 256, 0, stream>>>(offs, bsum, cursor, N);
    scatter_kernel<<<gEdge, 256, 0, stream>>>(ei, i64flag, cursor, el, E);

    for (int i = 0; i < 3; ++i) {
        float* sMlp = stats + (size_t)i * 512;        // gemm1 output stats
        float* sOut = stats + (size_t)i * 512 + 256;  // gemm2 output stats

        if (i == 0) {
            agg_kernel<false><<<gAgg, 512, 0, stream>>>(
                x, ea, el, offs, counts, nullptr, nullptr, nullptr, t1, N);
        } else {
            float* sPrev = stats + (size_t)(i - 1) * 512 + 256;
            agg_kernel<true><<<gAgg, 512, 0, stream>>>(
                t3, ea, el, offs, counts, sPrev, go + (i - 1) * 128, bo + (i - 1) * 128, t1, N);
        }
        gemm_kernel<false><<<gGemm, 256, 0, stream>>>(
            t1, Wt + (size_t)i * 16384, b1 + i * 128,
            nullptr, nullptr, nullptr, t2, sMlp, N);
        gemm_kernel<true><<<gGemm, 256, 0, stream>>>(
            t2, Wt + (size_t)(i + 3) * 16384, b2 + i * 128,
            sMlp, gm + i * 128, bm + i * 128, t3, sOut, N);
    }
    // final outer BN (no relu) -> out
    bn_kernel<<<gElem, 256, 0, stream>>>(t3, stats + 2 * 512 + 256, stats + 2 * 512 + 384,
                                         go + 256, bo + 256, out, N, nv4);
}